// Round 12
// baseline (229.437 us; speedup 1.0000x reference)
//
#include <hip/hip_runtime.h>
#include <hip/hip_bf16.h>
#include <stdint.h>

#define BATCH 16
#define D3 512
#define MAXP 64
#define NPATH 512

typedef short short8 __attribute__((ext_vector_type(8)));
typedef float floatx16 __attribute__((ext_vector_type(16)));
typedef unsigned short ushort4v __attribute__((ext_vector_type(4)));

__device__ __forceinline__ float fast_tanh(float x) {
  float e = __expf(2.f * x);
  return 1.f - 2.f / (e + 1.f);
}

__device__ __forceinline__ unsigned short f32_to_bf16_rn(float f) {
  unsigned u = __float_as_uint(f);
  u += 0x7fffu + ((u >> 16) & 1u);
  return (unsigned short)(u >> 16);
}
__device__ __forceinline__ float bf16_bits_to_f32(unsigned short s) {
  return __uint_as_float(((unsigned)s) << 16);
}

// Swizzled-layout index (in short8 units): matrix (R x 1024),
// tile (tr=r>>5, tk=k>>4), lane = ((k&15)>>3)*32 + (r&31). idx8 = (tr*64+tk)*64+lane.
__device__ __forceinline__ size_t swz_idx8(int r, int k) {
  return ((size_t)((r >> 5) * 64 + (k >> 4)) * 64) + ((k >> 3) & 1) * 32 + (r & 31);
}

// global -> LDS direct DMA, 16 B per lane; lds base wave-uniform, lane lands at +lane*16.
__device__ __forceinline__ void gl2lds16(const void* g, void* l) {
  auto* gp = reinterpret_cast<const __attribute__((address_space(1))) uint32_t*>(
      reinterpret_cast<uintptr_t>(g));
  auto* lp = reinterpret_cast<__attribute__((address_space(3))) uint32_t*>(
      (uint32_t)(uintptr_t)l);
  __builtin_amdgcn_global_load_lds(gp, lp, 16, 0, 0);
}

// ---------------------------------------------------------------------------
// Sigma stage 1 (one wave per h1 output) + fused x-transpose.
__global__ __launch_bounds__(256) void sigma_stage1(
    const float* __restrict__ x, const float* __restrict__ sW1,
    const float* __restrict__ sb1, float* __restrict__ h1,
    float* __restrict__ XT) {
  if (threadIdx.x < 64) {
    int e = blockIdx.x * 64 + threadIdx.x;
    int i = e >> 4, b = e & 15;
    XT[e] = x[b * 1024 + i];
  }
  int wv = threadIdx.x >> 6, lane = threadIdx.x & 63;
  int idx = blockIdx.x * 4 + wv;                // 0..1023
  int b = idx >> 6, u = idx & 63;
  const float* xr = x + b * 1024;
  const float* wr = sW1 + u * 1024;
  float s = 0.f;
  #pragma unroll
  for (int i = 0; i < 4; ++i) {
    int k = i * 256 + lane * 4;
    float4 xv = *(const float4*)(xr + k);
    float4 wv4 = *(const float4*)(wr + k);
    s = fmaf(xv.x, wv4.x, s); s = fmaf(xv.y, wv4.y, s);
    s = fmaf(xv.z, wv4.z, s); s = fmaf(xv.w, wv4.w, s);
  }
  #pragma unroll
  for (int off = 32; off > 0; off >>= 1) s += __shfl_down(s, off);
  if (lane == 0) h1[b * 64 + u] = fmaxf(s + sb1[u], 0.f);
}

// ---------------------------------------------------------------------------
// Fused kernel: blocks 0..255  -> L1 GEMM, full K=1024 per block (tile 32m x
//   16n), 4 per-segment accumulators summed in ks order (bit-identical to the
//   old split-K + reduce), then block-local tanh/split/swizzled X2t epilogue.
// block 256      -> sigma stage 2 (256-thread version, verified round 7).
// blocks 257..2304 -> W3 f32 -> hi/lo bf16 split (swizzled), independent.
__global__ __launch_bounds__(256) void gemm_l1_sigma2_w3split(
    const float* __restrict__ W1, const float* __restrict__ XT,
    unsigned short* __restrict__ X2th, unsigned short* __restrict__ X2tl,
    const float* __restrict__ h1,
    const float* __restrict__ sW2, const float* __restrict__ sb2,
    const float* __restrict__ sW3, const float* __restrict__ sb3,
    float* __restrict__ sigma_out, float* __restrict__ coeff,
    const float* __restrict__ W3, unsigned short* __restrict__ W3h,
    unsigned short* __restrict__ W3l) {
  if (blockIdx.x == 256) {
    // ---- sigma stage 2 (256 threads) ----
    __shared__ float lh1[BATCH * 64];
    __shared__ float h2[BATCH * 32];
    __shared__ float sg[BATCH * 16];
    int tid = threadIdx.x;
    #pragma unroll
    for (int i = 0; i < 4; ++i) lh1[tid + 256 * i] = h1[tid + 256 * i];
    __syncthreads();
    #pragma unroll
    for (int r = 0; r < 2; ++r) {
      int o = tid + 256 * r;
      int b = o >> 5, u = o & 31;
      const float* wr = sW2 + u * 64;
      float s = sb2[u];
      #pragma unroll 8
      for (int i = 0; i < 64; ++i) s = fmaf(lh1[b * 64 + i], wr[i], s);
      h2[b * 32 + u] = fmaxf(s, 0.f);
    }
    __syncthreads();
    {
      int b = tid >> 4, u = tid & 15;
      const float* wr = sW3 + u * 32;
      float s = sb3[u];
      #pragma unroll 8
      for (int i = 0; i < 32; ++i) s = fmaf(h2[b * 32 + i], wr[i], s);
      float t = tanhf(s);
      sg[b * 16 + u] = t;
      sigma_out[b * 16 + u] = t;
    }
    __syncthreads();
    if (tid < BATCH) {
      int b = tid;
      float sw = 0.f, pw = 0.f, dw = 0.f;
      for (int i = 0; i < 5; ++i) {
        sw += sg[b * 16 + i];
        pw += sg[b * 16 + 5 + i];
        dw += sg[b * 16 + 10 + i];
      }
      sw *= 0.2f; pw *= 0.2f; dw *= 0.2f;
      float tot = fabsf(sw) + fabsf(pw) + fabsf(dw) + 1e-8f;
      coeff[b * 4 + 0] = sw / tot;
      coeff[b * 4 + 1] = pw / tot;
      coeff[b * 4 + 2] = dw / tot;
      coeff[b * 4 + 3] = (sg[b * 16 + 15] + 1.f) * 0.5f;
    }
    return;
  }
  if (blockIdx.x > 256) {
    // ---- W3 split (independent blocks) ----
    int t = (blockIdx.x - 257) * 256 + threadIdx.x;  // 0..524287
    int lane = t & 63;
    int tile = t >> 6;
    int tm = tile >> 6, tk = tile & 63;           // KT = 64
    int m = tm * 32 + (lane & 31);
    int kb = tk * 16 + (lane >> 5) * 8;
    const float* src = W3 + (size_t)m * 1024 + kb;
    float4 v0 = *(const float4*)src;
    float4 v1 = *(const float4*)(src + 4);
    float f[8] = {v0.x, v0.y, v0.z, v0.w, v1.x, v1.y, v1.z, v1.w};
    short8 h, l;
    #pragma unroll
    for (int e = 0; e < 8; ++e) {
      unsigned short hi = f32_to_bf16_rn(f[e]);
      h[e] = (short)hi;
      l[e] = (short)f32_to_bf16_rn(f[e] - bf16_bits_to_f32(hi));
    }
    ((short8*)W3h)[t] = h;
    ((short8*)W3l)[t] = l;
    return;
  }
  // ---- L1 GEMM, full K, tile 32m x 16n ----
  __shared__ float Ast[64][33];                 // [k][m], 8.4 KiB
  __shared__ float Bs[64][16];
  const int tid = threadIdx.x;
  const int tx = tid & 15, ty = tid >> 4;       // n, m-pair index
  const int m0 = blockIdx.x * 32;
  float acc[2][4] = {};                         // [row][kseg]
  #pragma unroll
  for (int ks = 0; ks < 4; ++ks) {
    for (int k0 = 0; k0 < 256; k0 += 64) {
      const int kb = ks * 256 + k0;
      #pragma unroll
      for (int l = 0; l < 2; ++l) {
        int idx = l * 256 + tid;                // 0..511
        int i = idx >> 4;                       // row 0..31
        int j4 = (idx & 15) * 4;                // col 0..60
        float4 v = *(const float4*)(W1 + (size_t)(m0 + i) * 1024 + kb + j4);
        Ast[j4 + 0][i] = v.x; Ast[j4 + 1][i] = v.y;
        Ast[j4 + 2][i] = v.z; Ast[j4 + 3][i] = v.w;
      }
      {
        int kk = tid >> 2, j4 = (tid & 3) * 4;
        *(float4*)&Bs[kk][j4] = *(const float4*)(XT + (size_t)(kb + kk) * 16 + j4);
      }
      __syncthreads();
      #pragma unroll
      for (int kk = 0; kk < 64; ++kk) {
        float bv = Bs[kk][tx];
        float a0 = Ast[kk][ty * 2];
        float a1 = Ast[kk][ty * 2 + 1];
        acc[0][ks] = fmaf(a0, bv, acc[0][ks]);
        acc[1][ks] = fmaf(a1, bv, acc[1][ks]);
      }
      __syncthreads();
    }
  }
  // Sum segments in ks order (matches old l1red order), stash sums in LDS.
  float* S = &Ast[0][0];                        // reuse (≥512 floats)
  #pragma unroll
  for (int r = 0; r < 2; ++r) {
    float s = ((acc[r][0] + acc[r][1]) + acc[r][2]) + acc[r][3];
    S[(ty * 2 + r) * 16 + tx] = s;
  }
  __syncthreads();
  // Epilogue: 128 threads each handle one 4-m quad -> tanh/split/swizzled write.
  if (tid < 128) {
    int n = tid >> 3, mq = tid & 7;
    int mml = mq * 4;
    int mglob = m0 + mml;
    ushort4v h, l;
    #pragma unroll
    for (int e = 0; e < 4; ++e) {
      float v = fast_tanh(S[(mml + e) * 16 + n]);
      unsigned short hi = f32_to_bf16_rn(v);
      h[e] = hi;
      l[e] = f32_to_bf16_rn(v - bf16_bits_to_f32(hi));
    }
    int Bn = ((mglob >> 10) << 4) + n;          // k1*16 + n
    int Bk0 = mglob & 1023;
    size_t o = swz_idx8(Bn, Bk0) * 8 + (Bk0 & 7);
    *(ushort4v*)&X2th[o] = h;
    *(ushort4v*)&X2tl[o] = l;
  }
}

// ---------------------------------------------------------------------------
// L2a: LDS-dbuf MFMA, tile 64m x 128n (full N), 4-way split-K, 512 blocks 2/CU.
// A = W2 f32 staged global->reg->(in-register hi/lo bf16 split)->LDS.
// B = X2t split-bf16 via global_load_lds from swizzled layout.
// 8 stages of BK=32. Waves 2x2 (wm: m-half, wn: n-half); wave tile 32x64.
// Writes f32 partials Pp[(kseg*128+n)*8192 + m].
__global__ __launch_bounds__(256, 2) void mfma_l2(
    const float* __restrict__ W2,
    const unsigned short* __restrict__ Bh, const unsigned short* __restrict__ Bl,
    float* __restrict__ Pp) {
  const int by = blockIdx.x & 127, kseg = blockIdx.x >> 7;
  const int lane = threadIdx.x & 63, wave = threadIdx.x >> 6;
  const int wm = wave >> 1, wn = wave & 1;
  const int lr = lane & 31, kh = lane >> 5;
  // A staging map: thread -> (row ar, col ac..ac+7) of the 64x32 f32 stage tile.
  const int ar = threadIdx.x >> 2;              // 0..63
  const int ac = (threadIdx.x & 3) * 8;         // 0,8,16,24
  const int aktl = ac >> 4, akh = (ac >> 3) & 1;
  const int amt = ar >> 5, ar31 = ar & 31;
  const int m0 = by * 64, kb = kseg * 256;

  __shared__ __align__(16) short As[2][2][2][2][512];  // buf,ktl,mt,hl : 16 KiB
  __shared__ __align__(16) short Bs[2][2][4][2][512];  // buf,ktl,nt,hl : 32 KiB

  floatx16 acc[2];
  #pragma unroll
  for (int j = 0; j < 2; ++j)
    #pragma unroll
    for (int t = 0; t < 16; ++t) acc[j][t] = 0.f;

  const float* asrc = W2 + (size_t)(m0 + ar) * 1024 + kb + ac;
  float4 av0, av1;

#define A_LOAD(SI) do { const float* p_ = asrc + (SI) * 32; \
    av0 = *(const float4*)p_; av1 = *(const float4*)(p_ + 4); } while (0)
#define B_STAGE(SI) do { int buf_ = (SI) & 1; int tkb_ = kseg * 16 + (SI) * 2; \
    _Pragma("unroll") for (int q_ = 0; q_ < 4; ++q_) { \
      int ktl_ = q_ >> 1, hl_ = q_ & 1; \
      const unsigned short* gb_ = (hl_ ? Bl : Bh) + \
          (((size_t)(wave * 64) + tkb_ + ktl_) * 64 + lane) * 8; \
      gl2lds16(gb_, &Bs[buf_][ktl_][wave][hl_][0]); \
    } } while (0)
#define A_WRITE(SI) do { int buf_ = (SI) & 1; \
    float f_[8] = {av0.x, av0.y, av0.z, av0.w, av1.x, av1.y, av1.z, av1.w}; \
    short8 h_, l_; \
    _Pragma("unroll") for (int e_ = 0; e_ < 8; ++e_) { \
      unsigned short hi_ = f32_to_bf16_rn(f_[e_]); h_[e_] = (short)hi_; \
      l_[e_] = (short)f32_to_bf16_rn(f_[e_] - bf16_bits_to_f32(hi_)); } \
    *(short8*)&As[buf_][aktl][amt][0][(akh * 32 + ar31) * 8] = h_; \
    *(short8*)&As[buf_][aktl][amt][1][(akh * 32 + ar31) * 8] = l_; } while (0)

  A_LOAD(0); B_STAGE(0); A_WRITE(0);
  for (int s = 0; s < 8; ++s) {
    __syncthreads();
    if (s + 1 < 8) { A_LOAD(s + 1); B_STAGE(s + 1); }
    const int buf = s & 1;
    #pragma unroll
    for (int ktl = 0; ktl < 2; ++ktl) {
      short8 a0 = *(const short8*)&As[buf][ktl][wm][0][lane * 8];
      short8 a1 = *(const short8*)&As[buf][ktl][wm][1][lane * 8];
      #pragma unroll
      for (int j = 0; j < 2; ++j) {
        short8 b0 = *(const short8*)&Bs[buf][ktl][wn * 2 + j][0][lane * 8];
        short8 b1 = *(const short8*)&Bs[buf][ktl][wn * 2 + j][1][lane * 8];
        acc[j] = __builtin_amdgcn_mfma_f32_32x32x16_bf16(a0, b0, acc[j], 0, 0, 0);
        acc[j] = __builtin_amdgcn_mfma_f32_32x32x16_bf16(a0, b1, acc[j], 0, 0, 0);
        acc[j] = __builtin_amdgcn_mfma_f32_32x32x16_bf16(a1, b0, acc[j], 0, 0, 0);
      }
    }
    if (s + 1 < 8) A_WRITE(s + 1);
  }
#undef A_LOAD
#undef B_STAGE
#undef A_WRITE

  #pragma unroll
  for (int j = 0; j < 2; ++j) {
    int n = wn * 64 + j * 32 + lr;
    int mbase = m0 + wm * 32 + 4 * kh;
    #pragma unroll
    for (int rq = 0; rq < 4; ++rq) {
      float4 v4;
      v4.x = acc[j][rq * 4 + 0];
      v4.y = acc[j][rq * 4 + 1];
      v4.z = acc[j][rq * 4 + 2];
      v4.w = acc[j][rq * 4 + 3];
      *(float4*)&Pp[(size_t)(kseg * 128 + n) * 8192 + mbase + rq * 8] = v4;
    }
  }
}

// ---------------------------------------------------------------------------
// L2b: reduce 4 K-segments + tanh + split + swizzled X3t write.
__global__ __launch_bounds__(256) void gemm_l2red(
    const float* __restrict__ Pp, unsigned short* __restrict__ X3th,
    unsigned short* __restrict__ X3tl) {
  int t = blockIdx.x * 256 + threadIdx.x;       // 262144 = 128 n x 2048 m-quads
  int n = t >> 11, mq = t & 2047;
  int m0 = mq * 4;
  float4 s = make_float4(0.f, 0.f, 0.f, 0.f);
  #pragma unroll
  for (int ks = 0; ks < 4; ++ks) {
    float4 v = *(const float4*)&Pp[(size_t)(ks * 128 + n) * 8192 + m0];
    s.x += v.x; s.y += v.y; s.z += v.z; s.w += v.w;
  }
  ushort4v h, l;
  #pragma unroll
  for (int e = 0; e < 4; ++e) {
    float v = fast_tanh((&s.x)[e]);
    unsigned short hi = f32_to_bf16_rn(v);
    h[e] = hi;
    l[e] = f32_to_bf16_rn(v - bf16_bits_to_f32(hi));
  }
  int Bn = ((m0 >> 10) << 7) + n;               // k2*128 + n
  int Bk0 = m0 & 1023;
  size_t o = swz_idx8(Bn, Bk0) * 8 + (Bk0 & 7);
  *(ushort4v*)&X3th[o] = h;
  *(ushort4v*)&X3tl[o] = l;
}

// ---------------------------------------------------------------------------
// L3: LDS-dbuf split-bf16 MFMA, 128x128 tile, full K, 256 blocks x 512 threads.
// A = pre-split W3h/W3l via global_load_lds (swizzled layout).
// B = X3t split-bf16 via global_load_lds.
// XCD swizzle: xcd = bid&7 gets logical blocks [xcd*32, xcd*32+32).
// 32 stages of BK=32. Waves 2x4; wave tile 64x32. 64 KiB LDS.
// Writes Yt[n][m] (transposed) + fused per-column stats partials.
__global__ __launch_bounds__(512, 1) void mfma_l3(
    const unsigned short* __restrict__ Ah, const unsigned short* __restrict__ Al,
    const unsigned short* __restrict__ Bh, const unsigned short* __restrict__ Bl,
    float* __restrict__ Yt,
    float* __restrict__ Qp1, float* __restrict__ Qp2, float* __restrict__ Qpc) {
  const int lg = (blockIdx.x & 7) * 32 + (blockIdx.x >> 3);  // logical 0..255
  const int by = lg >> 3;                       // 0..31  (m-tiles of 128)
  const int bx = lg & 7;                        // 0..7   (n-tiles of 128)
  const int lane = threadIdx.x & 63, wave = threadIdx.x >> 6;  // wave 0..7
  const int wm = wave >> 2, wn = wave & 3;
  const int lr = lane & 31, kh = lane >> 5;

  __shared__ __align__(16) short As[2][2][4][2][512];  // 32 KiB
  __shared__ __align__(16) short Bs[2][2][4][2][512];  // 32 KiB

  floatx16 acc[2];
  #pragma unroll
  for (int i = 0; i < 2; ++i)
    #pragma unroll
    for (int t = 0; t < 16; ++t) acc[i][t] = 0.f;

#define STAGE(SI) do { int buf_ = (SI) & 1, kt0_ = (SI) * 2; \
    _Pragma("unroll") for (int q_ = 0; q_ < 4; ++q_) { \
      int f_ = wave * 4 + q_; \
      if (f_ < 16) { \
        int hl_ = f_ & 1, mt_ = (f_ >> 1) & 3, ktl_ = f_ >> 3; \
        const unsigned short* gb_ = (hl_ ? Al : Ah) + \
            (((size_t)(by * 4 + mt_) * 64 + kt0_ + ktl_) * 64 + lane) * 8; \
        gl2lds16(gb_, &As[buf_][ktl_][mt_][hl_][0]); \
      } else { \
        int r_ = f_ - 16, hl_ = r_ & 1, nt_ = (r_ >> 1) & 3, ktl_ = r_ >> 3; \
        const unsigned short* gb_ = (hl_ ? Bl : Bh) + \
            (((size_t)(bx * 4 + nt_) * 64 + kt0_ + ktl_) * 64 + lane) * 8; \
        gl2lds16(gb_, &Bs[buf_][ktl_][nt_][hl_][0]); \
      } } } while (0)

  STAGE(0);
  for (int s = 0; s < 32; ++s) {
    __syncthreads();
    if (s + 1 < 32) STAGE(s + 1);
    const int buf = s & 1;
    #pragma unroll
    for (int ktl = 0; ktl < 2; ++ktl) {
      short8 a[2][2], b[2];
      #pragma unroll
      for (int i = 0; i < 2; ++i) {
        a[i][0] = *(const short8*)&As[buf][ktl][wm * 2 + i][0][lane * 8];
        a[i][1] = *(const short8*)&As[buf][ktl][wm * 2 + i][1][lane * 8];
      }
      b[0] = *(const short8*)&Bs[buf][ktl][wn][0][lane * 8];
      b[1] = *(const short8*)&Bs[buf][ktl][wn][1][lane * 8];
      #pragma unroll
      for (int i = 0; i < 2; ++i) {
        acc[i] = __builtin_amdgcn_mfma_f32_32x32x16_bf16(a[i][0], b[0], acc[i], 0, 0, 0);
        acc[i] = __builtin_amdgcn_mfma_f32_32x32x16_bf16(a[i][0], b[1], acc[i], 0, 0, 0);
        acc[i] = __builtin_amdgcn_mfma_f32_32x32x16_bf16(a[i][1], b[0], acc[i], 0, 0, 0);
      }
    }
  }
#undef STAGE

  // Epilogue: Yt[n*4096+m] float4 stores + per-column stats.
  float st1 = 0.f, st2 = 0.f, stc = 0.f;
  int n = bx * 128 + wn * 32 + lr;
  #pragma unroll
  for (int i = 0; i < 2; ++i) {
    int mbase = by * 128 + (wm * 2 + i) * 32 + 4 * kh;
    #pragma unroll
    for (int rq = 0; rq < 4; ++rq) {
      float4 v4;
      v4.x = acc[i][rq * 4 + 0];
      v4.y = acc[i][rq * 4 + 1];
      v4.z = acc[i][rq * 4 + 2];
      v4.w = acc[i][rq * 4 + 3];
      *(float4*)&Yt[(size_t)n * 4096 + mbase + rq * 8] = v4;
      #pragma unroll
      for (int e = 0; e < 4; ++e) {
        float v = (&v4.x)[e];
        st1 += v;
        st2 = fmaf(v, v, st2);
        stc += (fabsf(v) < 0.1f) ? 1.f : 0.f;
      }
    }
  }
  __syncthreads();                              // all As/Bs reads done
  // Stats arrays alias the (now dead) As buffer -> LDS stays at 64 KiB.
  float* sS1 = (float*)&As[0][0][0][0][0];
  float* sS2 = sS1 + 128;
  float* sC  = sS1 + 256;
  if (threadIdx.x < 128) { sS1[threadIdx.x] = 0.f; sS2[threadIdx.x] = 0.f; sC[threadIdx.x] = 0.f; }
  __syncthreads();
  {
    int cl = wn * 32 + lr;
    atomicAdd(&sS1[cl], st1);
    atomicAdd(&sS2[cl], st2);
    atomicAdd(&sC[cl], stc);
  }
  __syncthreads();
  if (threadIdx.x < 128) {
    int part = by & 3, k3 = by >> 2;
    size_t qo = ((size_t)part * 8 + k3) * 1024 + bx * 128 + threadIdx.x;
    Qp1[qo] = sS1[threadIdx.x];
    Qp2[qo] = sS2[threadIdx.x];
    Qpc[qo] = sC[threadIdx.x];
  }
}

// ---------------------------------------------------------------------------
// Fused selection + collapse. Each of the 8 chunk-blocks per batch redundantly
// computes the same top-64 selection (set is order-independent), then collapses.
__global__ __launch_bounds__(256) void collapse2(
    const float* __restrict__ Yt,
    const float* __restrict__ Qp1, const float* __restrict__ Qp2,
    const float* __restrict__ Qpc, const float* __restrict__ coeff,
    float* __restrict__ out) {
  int b = blockIdx.x >> 3, chunk = blockIdx.x & 7;
  int lane = threadIdx.x & 63, wv = threadIdx.x >> 6;
  int tid = threadIdx.x;
  __shared__ float q[NPATH];
  __shared__ int ls[MAXP];
  __shared__ int cnt;
  __shared__ float s_sum[4][64], s_best[4][64], s_ba[4][64];
  if (tid == 0) cnt = 0;
  float c0 = coeff[b * 4 + 0], c1 = coeff[b * 4 + 1], c2w = coeff[b * 4 + 2];
  for (int p = tid; p < NPATH; p += 256) {
    int k3 = p >> 6, k2 = (p >> 3) & 7, k1 = p & 7;
    int c2 = k2 * 128 + k1 * 16 + b;
    float S1 = 0.f, S2 = 0.f, C = 0.f;
    #pragma unroll
    for (int part = 0; part < 4; ++part) {
      size_t qo = ((size_t)part * 8 + k3) * 1024 + c2;
      S1 += Qp1[qo]; S2 += Qp2[qo]; C += Qpc[qo];
    }
    float strength = sqrtf(S2);
    float sparsity = C * (1.f / 512.f);
    float diversity = (S2 - S1 * S1 * (1.f / 512.f)) * (1.f / 511.f);
    q[p] = c0 * strength + c1 * sparsity + c2w * diversity;
  }
  __syncthreads();
  for (int p = tid; p < NPATH; p += 256) {
    float qp = q[p];
    int rank = 0;
    #pragma unroll 8
    for (int j = 0; j < NPATH; ++j) {
      float qj = q[j];
      rank += (qj > qp) || (qj == qp && j < p);
    }
    if (rank < MAXP) {
      int sl = atomicAdd(&cnt, 1);
      ls[sl] = p;
    }
  }
  __syncthreads();
  int o3 = chunk * 64 + lane;
  float sum = 0.f, best = 0.f, besta = -1.f;
  #pragma unroll 4
  for (int j = wv * 16; j < wv * 16 + 16; ++j) {
    int p = ls[j];
    int k3 = p >> 6, k2 = (p >> 3) & 7, k1 = p & 7;
    int col = k2 * 128 + k1 * 16 + b;
    float v = Yt[(size_t)col * 4096 + k3 * 512 + o3];
    sum += v;
    float a = fabsf(v);
    if (a > besta) { besta = a; best = v; }
  }
  s_sum[wv][lane] = sum; s_best[wv][lane] = best; s_ba[wv][lane] = besta;
  __syncthreads();
  if (tid < 64) {
    float S = 0.f, BV = 0.f, BA = -1.f;
    #pragma unroll
    for (int w2 = 0; w2 < 4; ++w2) {
      S += s_sum[w2][tid];
      if (s_ba[w2][tid] > BA) { BA = s_ba[w2][tid]; BV = s_best[w2][tid]; }
    }
    float alpha = coeff[b * 4 + 3];
    out[b * 512 + chunk * 64 + tid] = (1.f - alpha) * (S * (1.f / 64.f)) + alpha * BV;
  }
}

// ---------------------------------------------------------------------------
extern "C" void kernel_launch(void* const* d_in, const int* in_sizes, int n_in,
                              void* d_out, int out_size, void* d_ws, size_t ws_size,
                              hipStream_t stream) {
  const float* x   = (const float*)d_in[0];
  const float* W1  = (const float*)d_in[1];
  const float* W2  = (const float*)d_in[2];
  const float* W3  = (const float*)d_in[3];
  const float* sW1 = (const float*)d_in[4];
  const float* sb1 = (const float*)d_in[5];
  const float* sW2 = (const float*)d_in[6];
  const float* sb2 = (const float*)d_in[7];
  const float* sW3 = (const float*)d_in[8];
  const float* sb3 = (const float*)d_in[9];
  float* out = (float*)d_out;                   // 16*512 outputs + 16*16 sigma

  char* w = (char*)d_ws;
  float* XT = (float*)w;                       w += 65536;     // 1024x16 f32
  unsigned short* W3h = (unsigned short*)w;    w += 8388608;   // 4096x1024 bf16 swz
  unsigned short* W3l = (unsigned short*)w;    w += 8388608;
  unsigned short* X2th = (unsigned short*)w;   w += 262144;    // 128x1024 bf16 swz
  unsigned short* X2tl = (unsigned short*)w;   w += 262144;
  unsigned short* X3th = (unsigned short*)w;   w += 2097152;   // 1024x1024 bf16 swz
  unsigned short* X3tl = (unsigned short*)w;   w += 2097152;
  float* Yt    = (float*)w;                    w += 16777216;  // 1024x4096 f32 (transposed)
  float* Pp    = (float*)w;                    w += 16777216;  // 4x128x8192 f32 (L2 partials)
  float* coeff = (float*)w;                    w += 256;
  float* Qp1   = (float*)w;                    w += 131072;    // 4x8x1024 f32
  float* Qp2   = (float*)w;                    w += 131072;
  float* Qpc   = (float*)w;                    w += 131072;
  float* h1    = (float*)w;                    w += 4096;

  // 1: sigma stage 1 + XT
  sigma_stage1<<<256, 256, 0, stream>>>(x, sW1, sb1, h1, XT);

  // 2: L1 full-K GEMM (block-local reduce/tanh/split/swizzle) + sigma stage 2
  //    + W3 split (one launch)
  gemm_l1_sigma2_w3split<<<2305, 256, 0, stream>>>(
      W1, XT, X2th, X2tl, h1, sW2, sb2, sW3, sb3, out + 8192, coeff,
      W3, W3h, W3l);

  // 3: MFMA 64x128, full-N, split-K 4 (512 blocks, 2/CU), in-kernel W2 split
  mfma_l2<<<512, 256, 0, stream>>>(W2, X2th, X2tl, Pp);

  // 4: L2 reduce -> X3t
  gemm_l2red<<<1024, 256, 0, stream>>>(Pp, X3th, X3tl);

  // 5: MFMA 128x128, full K (256 blocks x 512 thr, XCD-swizzled)
  mfma_l3<<<256, 512, 0, stream>>>(W3h, W3l, X3th, X3tl, Yt, Qp1, Qp2, Qpc);

  // 6: fused selection + collapse
  collapse2<<<128, 256, 0, stream>>>(Yt, Qp1, Qp2, Qpc, coeff, out);
}

// Round 13
// 216.659 us; speedup vs baseline: 1.0590x; 1.0590x over previous
//
#include <hip/hip_runtime.h>
#include <hip/hip_bf16.h>
#include <stdint.h>

#define BATCH 16
#define D3 512
#define MAXP 64
#define NPATH 512

typedef short short8 __attribute__((ext_vector_type(8)));
typedef float floatx16 __attribute__((ext_vector_type(16)));
typedef unsigned short ushort4v __attribute__((ext_vector_type(4)));

__device__ __forceinline__ float fast_tanh(float x) {
  float e = __expf(2.f * x);
  return 1.f - 2.f / (e + 1.f);
}

__device__ __forceinline__ unsigned short f32_to_bf16_rn(float f) {
  unsigned u = __float_as_uint(f);
  u += 0x7fffu + ((u >> 16) & 1u);
  return (unsigned short)(u >> 16);
}
__device__ __forceinline__ float bf16_bits_to_f32(unsigned short s) {
  return __uint_as_float(((unsigned)s) << 16);
}

// Swizzled-layout index (in short8 units): matrix (R x 1024),
// tile (tr=r>>5, tk=k>>4), lane = ((k&15)>>3)*32 + (r&31). idx8 = (tr*64+tk)*64+lane.
__device__ __forceinline__ size_t swz_idx8(int r, int k) {
  return ((size_t)((r >> 5) * 64 + (k >> 4)) * 64) + ((k >> 3) & 1) * 32 + (r & 31);
}

// global -> LDS direct DMA, 16 B per lane; lds base wave-uniform, lane lands at +lane*16.
__device__ __forceinline__ void gl2lds16(const void* g, void* l) {
  auto* gp = reinterpret_cast<const __attribute__((address_space(1))) uint32_t*>(
      reinterpret_cast<uintptr_t>(g));
  auto* lp = reinterpret_cast<__attribute__((address_space(3))) uint32_t*>(
      (uint32_t)(uintptr_t)l);
  __builtin_amdgcn_global_load_lds(gp, lp, 16, 0, 0);
}

// ---------------------------------------------------------------------------
// Sigma stage 1 (one wave per h1 output) + fused x-transpose.
__global__ __launch_bounds__(256) void sigma_stage1(
    const float* __restrict__ x, const float* __restrict__ sW1,
    const float* __restrict__ sb1, float* __restrict__ h1,
    float* __restrict__ XT) {
  if (threadIdx.x < 64) {
    int e = blockIdx.x * 64 + threadIdx.x;
    int i = e >> 4, b = e & 15;
    XT[e] = x[b * 1024 + i];
  }
  int wv = threadIdx.x >> 6, lane = threadIdx.x & 63;
  int idx = blockIdx.x * 4 + wv;                // 0..1023
  int b = idx >> 6, u = idx & 63;
  const float* xr = x + b * 1024;
  const float* wr = sW1 + u * 1024;
  float s = 0.f;
  #pragma unroll
  for (int i = 0; i < 4; ++i) {
    int k = i * 256 + lane * 4;
    float4 xv = *(const float4*)(xr + k);
    float4 wv4 = *(const float4*)(wr + k);
    s = fmaf(xv.x, wv4.x, s); s = fmaf(xv.y, wv4.y, s);
    s = fmaf(xv.z, wv4.z, s); s = fmaf(xv.w, wv4.w, s);
  }
  #pragma unroll
  for (int off = 32; off > 0; off >>= 1) s += __shfl_down(s, off);
  if (lane == 0) h1[b * 64 + u] = fmaxf(s + sb1[u], 0.f);
}

// ---------------------------------------------------------------------------
// L1a + sigma stage 2 fused: blocks 0..255 run the split-K f32 GEMM
// (tile 128m x 16n, K range 256 -> Xp[(kseg*16+n)*8192+m]); block 256 runs
// sigma stage 2 (256-thread version) concurrently.
__global__ __launch_bounds__(256) void gemm_l1a_sigma2(
    const float* __restrict__ W1, const float* __restrict__ XT,
    float* __restrict__ Xp,
    const float* __restrict__ h1,
    const float* __restrict__ sW2, const float* __restrict__ sb2,
    const float* __restrict__ sW3, const float* __restrict__ sb3,
    float* __restrict__ sigma_out, float* __restrict__ coeff) {
  if (blockIdx.x == 256) {
    // ---- sigma stage 2 (256 threads) ----
    __shared__ float lh1[BATCH * 64];
    __shared__ float h2[BATCH * 32];
    __shared__ float sg[BATCH * 16];
    int tid = threadIdx.x;
    #pragma unroll
    for (int i = 0; i < 4; ++i) lh1[tid + 256 * i] = h1[tid + 256 * i];
    __syncthreads();
    #pragma unroll
    for (int r = 0; r < 2; ++r) {
      int o = tid + 256 * r;
      int b = o >> 5, u = o & 31;
      const float* wr = sW2 + u * 64;
      float s = sb2[u];
      #pragma unroll 8
      for (int i = 0; i < 64; ++i) s = fmaf(lh1[b * 64 + i], wr[i], s);
      h2[b * 32 + u] = fmaxf(s, 0.f);
    }
    __syncthreads();
    {
      int b = tid >> 4, u = tid & 15;
      const float* wr = sW3 + u * 32;
      float s = sb3[u];
      #pragma unroll 8
      for (int i = 0; i < 32; ++i) s = fmaf(h2[b * 32 + i], wr[i], s);
      float t = tanhf(s);
      sg[b * 16 + u] = t;
      sigma_out[b * 16 + u] = t;
    }
    __syncthreads();
    if (tid < BATCH) {
      int b = tid;
      float sw = 0.f, pw = 0.f, dw = 0.f;
      for (int i = 0; i < 5; ++i) {
        sw += sg[b * 16 + i];
        pw += sg[b * 16 + 5 + i];
        dw += sg[b * 16 + 10 + i];
      }
      sw *= 0.2f; pw *= 0.2f; dw *= 0.2f;
      float tot = fabsf(sw) + fabsf(pw) + fabsf(dw) + 1e-8f;
      coeff[b * 4 + 0] = sw / tot;
      coeff[b * 4 + 1] = pw / tot;
      coeff[b * 4 + 2] = dw / tot;
      coeff[b * 4 + 3] = (sg[b * 16 + 15] + 1.f) * 0.5f;
    }
    return;
  }
  // ---- L1a GEMM (unchanged hot loop) ----
  __shared__ float Ast[64][132];
  __shared__ float Bs[64][16];
  const int tid = threadIdx.x;
  const int tx = tid & 15, ty = tid >> 4;
  const int mblk = blockIdx.x >> 2, kseg = blockIdx.x & 3;
  const int m0 = mblk * 128, kb = kseg * 256;
  float acc[8] = {};
  for (int k0 = 0; k0 < 256; k0 += 64) {
    #pragma unroll
    for (int l = 0; l < 8; ++l) {
      int idx = l * 256 + tid;
      int i = idx >> 4;
      int j4 = (idx & 15) * 4;
      float4 v = *(const float4*)(W1 + (size_t)(m0 + i) * 1024 + kb + k0 + j4);
      Ast[j4 + 0][i] = v.x; Ast[j4 + 1][i] = v.y;
      Ast[j4 + 2][i] = v.z; Ast[j4 + 3][i] = v.w;
    }
    {
      int kk = tid >> 2, j4 = (tid & 3) * 4;
      *(float4*)&Bs[kk][j4] = *(const float4*)(XT + (size_t)(kb + k0 + kk) * 16 + j4);
    }
    __syncthreads();
    #pragma unroll
    for (int kk = 0; kk < 64; ++kk) {
      float b = Bs[kk][tx];
      float4 a0 = *(const float4*)&Ast[kk][ty * 8];
      float4 a1 = *(const float4*)&Ast[kk][ty * 8 + 4];
      acc[0] = fmaf(a0.x, b, acc[0]); acc[1] = fmaf(a0.y, b, acc[1]);
      acc[2] = fmaf(a0.z, b, acc[2]); acc[3] = fmaf(a0.w, b, acc[3]);
      acc[4] = fmaf(a1.x, b, acc[4]); acc[5] = fmaf(a1.y, b, acc[5]);
      acc[6] = fmaf(a1.z, b, acc[6]); acc[7] = fmaf(a1.w, b, acc[7]);
    }
    __syncthreads();
  }
  float* dst = Xp + (size_t)(kseg * 16 + tx) * 8192 + m0 + ty * 8;
  *(float4*)dst = make_float4(acc[0], acc[1], acc[2], acc[3]);
  *(float4*)(dst + 4) = make_float4(acc[4], acc[5], acc[6], acc[7]);
}

// ---------------------------------------------------------------------------
// L1b (fused): blocks 0..127  -> reduce 4 K-segments + tanh + split + swizzled
//                               X2t write (N=128 rows).
//              blocks 128..2175 -> W3 f32 -> hi/lo bf16 split, swizzled layout
//                               (one short8 per thread). Memory-bound, no LDS.
__global__ __launch_bounds__(256) void gemm_l1red_w3split(
    const float* __restrict__ Xp, unsigned short* __restrict__ X2th,
    unsigned short* __restrict__ X2tl,
    const float* __restrict__ W3, unsigned short* __restrict__ W3h,
    unsigned short* __restrict__ W3l) {
  if (blockIdx.x >= 128) {
    int t = (blockIdx.x - 128) * 256 + threadIdx.x;  // 0..524287
    int lane = t & 63;
    int tile = t >> 6;
    int tm = tile >> 6, tk = tile & 63;           // KT = 64
    int m = tm * 32 + (lane & 31);
    int kb = tk * 16 + (lane >> 5) * 8;
    const float* src = W3 + (size_t)m * 1024 + kb;
    float4 v0 = *(const float4*)src;
    float4 v1 = *(const float4*)(src + 4);
    float f[8] = {v0.x, v0.y, v0.z, v0.w, v1.x, v1.y, v1.z, v1.w};
    short8 h, l;
    #pragma unroll
    for (int e = 0; e < 8; ++e) {
      unsigned short hi = f32_to_bf16_rn(f[e]);
      h[e] = (short)hi;
      l[e] = (short)f32_to_bf16_rn(f[e] - bf16_bits_to_f32(hi));
    }
    ((short8*)W3h)[t] = h;
    ((short8*)W3l)[t] = l;
    return;
  }
  int t = blockIdx.x * 256 + threadIdx.x;       // 32768 = 16 n x 2048 m-quads
  int n = t >> 11, mq = t & 2047;
  int m0 = mq * 4;
  float4 s = make_float4(0.f, 0.f, 0.f, 0.f);
  #pragma unroll
  for (int ks = 0; ks < 4; ++ks) {
    float4 v = *(const float4*)&Xp[(size_t)(ks * 16 + n) * 8192 + m0];
    s.x += v.x; s.y += v.y; s.z += v.z; s.w += v.w;
  }
  ushort4v h, l;
  #pragma unroll
  for (int e = 0; e < 4; ++e) {
    float v = fast_tanh((&s.x)[e]);
    unsigned short hi = f32_to_bf16_rn(v);
    h[e] = hi;
    l[e] = f32_to_bf16_rn(v - bf16_bits_to_f32(hi));
  }
  int Bn = ((m0 >> 10) << 4) + n;               // k1*16 + n
  int Bk0 = m0 & 1023;
  size_t o = swz_idx8(Bn, Bk0) * 8 + (Bk0 & 7);
  *(ushort4v*)&X2th[o] = h;
  *(ushort4v*)&X2tl[o] = l;
}

// ---------------------------------------------------------------------------
// L2a: LDS-dbuf MFMA, tile 64m x 128n (full N), 4-way split-K, 512 blocks 2/CU.
// A = W2 f32 staged global->reg->(in-register hi/lo bf16 split)->LDS.
// B = X2t split-bf16 via global_load_lds from swizzled layout.
// 8 stages of BK=32. Waves 2x2 (wm: m-half, wn: n-half); wave tile 32x64.
// Writes f32 partials Pp[(kseg*128+n)*8192 + m].
__global__ __launch_bounds__(256, 2) void mfma_l2(
    const float* __restrict__ W2,
    const unsigned short* __restrict__ Bh, const unsigned short* __restrict__ Bl,
    float* __restrict__ Pp) {
  const int by = blockIdx.x & 127, kseg = blockIdx.x >> 7;
  const int lane = threadIdx.x & 63, wave = threadIdx.x >> 6;
  const int wm = wave >> 1, wn = wave & 1;
  const int lr = lane & 31, kh = lane >> 5;
  // A staging map: thread -> (row ar, col ac..ac+7) of the 64x32 f32 stage tile.
  const int ar = threadIdx.x >> 2;              // 0..63
  const int ac = (threadIdx.x & 3) * 8;         // 0,8,16,24
  const int aktl = ac >> 4, akh = (ac >> 3) & 1;
  const int amt = ar >> 5, ar31 = ar & 31;
  const int m0 = by * 64, kb = kseg * 256;

  __shared__ __align__(16) short As[2][2][2][2][512];  // buf,ktl,mt,hl : 16 KiB
  __shared__ __align__(16) short Bs[2][2][4][2][512];  // buf,ktl,nt,hl : 32 KiB

  floatx16 acc[2];
  #pragma unroll
  for (int j = 0; j < 2; ++j)
    #pragma unroll
    for (int t = 0; t < 16; ++t) acc[j][t] = 0.f;

  const float* asrc = W2 + (size_t)(m0 + ar) * 1024 + kb + ac;
  float4 av0, av1;

#define A_LOAD(SI) do { const float* p_ = asrc + (SI) * 32; \
    av0 = *(const float4*)p_; av1 = *(const float4*)(p_ + 4); } while (0)
#define B_STAGE(SI) do { int buf_ = (SI) & 1; int tkb_ = kseg * 16 + (SI) * 2; \
    _Pragma("unroll") for (int q_ = 0; q_ < 4; ++q_) { \
      int ktl_ = q_ >> 1, hl_ = q_ & 1; \
      const unsigned short* gb_ = (hl_ ? Bl : Bh) + \
          (((size_t)(wave * 64) + tkb_ + ktl_) * 64 + lane) * 8; \
      gl2lds16(gb_, &Bs[buf_][ktl_][wave][hl_][0]); \
    } } while (0)
#define A_WRITE(SI) do { int buf_ = (SI) & 1; \
    float f_[8] = {av0.x, av0.y, av0.z, av0.w, av1.x, av1.y, av1.z, av1.w}; \
    short8 h_, l_; \
    _Pragma("unroll") for (int e_ = 0; e_ < 8; ++e_) { \
      unsigned short hi_ = f32_to_bf16_rn(f_[e_]); h_[e_] = (short)hi_; \
      l_[e_] = (short)f32_to_bf16_rn(f_[e_] - bf16_bits_to_f32(hi_)); } \
    *(short8*)&As[buf_][aktl][amt][0][(akh * 32 + ar31) * 8] = h_; \
    *(short8*)&As[buf_][aktl][amt][1][(akh * 32 + ar31) * 8] = l_; } while (0)

  A_LOAD(0); B_STAGE(0); A_WRITE(0);
  for (int s = 0; s < 8; ++s) {
    __syncthreads();
    if (s + 1 < 8) { A_LOAD(s + 1); B_STAGE(s + 1); }
    const int buf = s & 1;
    #pragma unroll
    for (int ktl = 0; ktl < 2; ++ktl) {
      short8 a0 = *(const short8*)&As[buf][ktl][wm][0][lane * 8];
      short8 a1 = *(const short8*)&As[buf][ktl][wm][1][lane * 8];
      #pragma unroll
      for (int j = 0; j < 2; ++j) {
        short8 b0 = *(const short8*)&Bs[buf][ktl][wn * 2 + j][0][lane * 8];
        short8 b1 = *(const short8*)&Bs[buf][ktl][wn * 2 + j][1][lane * 8];
        acc[j] = __builtin_amdgcn_mfma_f32_32x32x16_bf16(a0, b0, acc[j], 0, 0, 0);
        acc[j] = __builtin_amdgcn_mfma_f32_32x32x16_bf16(a0, b1, acc[j], 0, 0, 0);
        acc[j] = __builtin_amdgcn_mfma_f32_32x32x16_bf16(a1, b0, acc[j], 0, 0, 0);
      }
    }
    if (s + 1 < 8) A_WRITE(s + 1);
  }
#undef A_LOAD
#undef B_STAGE
#undef A_WRITE

  #pragma unroll
  for (int j = 0; j < 2; ++j) {
    int n = wn * 64 + j * 32 + lr;
    int mbase = m0 + wm * 32 + 4 * kh;
    #pragma unroll
    for (int rq = 0; rq < 4; ++rq) {
      float4 v4;
      v4.x = acc[j][rq * 4 + 0];
      v4.y = acc[j][rq * 4 + 1];
      v4.z = acc[j][rq * 4 + 2];
      v4.w = acc[j][rq * 4 + 3];
      *(float4*)&Pp[(size_t)(kseg * 128 + n) * 8192 + mbase + rq * 8] = v4;
    }
  }
}

// ---------------------------------------------------------------------------
// L2b: reduce 4 K-segments + tanh + split + swizzled X3t write.
__global__ __launch_bounds__(256) void gemm_l2red(
    const float* __restrict__ Pp, unsigned short* __restrict__ X3th,
    unsigned short* __restrict__ X3tl) {
  int t = blockIdx.x * 256 + threadIdx.x;       // 262144 = 128 n x 2048 m-quads
  int n = t >> 11, mq = t & 2047;
  int m0 = mq * 4;
  float4 s = make_float4(0.f, 0.f, 0.f, 0.f);
  #pragma unroll
  for (int ks = 0; ks < 4; ++ks) {
    float4 v = *(const float4*)&Pp[(size_t)(ks * 128 + n) * 8192 + m0];
    s.x += v.x; s.y += v.y; s.z += v.z; s.w += v.w;
  }
  ushort4v h, l;
  #pragma unroll
  for (int e = 0; e < 4; ++e) {
    float v = fast_tanh((&s.x)[e]);
    unsigned short hi = f32_to_bf16_rn(v);
    h[e] = hi;
    l[e] = f32_to_bf16_rn(v - bf16_bits_to_f32(hi));
  }
  int Bn = ((m0 >> 10) << 7) + n;               // k2*128 + n
  int Bk0 = m0 & 1023;
  size_t o = swz_idx8(Bn, Bk0) * 8 + (Bk0 & 7);
  *(ushort4v*)&X3th[o] = h;
  *(ushort4v*)&X3tl[o] = l;
}

// ---------------------------------------------------------------------------
// L3: LDS-dbuf split-bf16 MFMA, 128x128 tile, full K, 256 blocks x 512 threads.
// A = pre-split W3h/W3l via global_load_lds (swizzled layout).
// B = X3t split-bf16 via global_load_lds.
// XCD swizzle: xcd = bid&7 gets logical blocks [xcd*32, xcd*32+32).
// 32 stages of BK=32. Waves 2x4; wave tile 64x32. 64 KiB LDS.
// Writes Yt[n][m] (transposed) + fused per-column stats partials.
__global__ __launch_bounds__(512, 1) void mfma_l3(
    const unsigned short* __restrict__ Ah, const unsigned short* __restrict__ Al,
    const unsigned short* __restrict__ Bh, const unsigned short* __restrict__ Bl,
    float* __restrict__ Yt,
    float* __restrict__ Qp1, float* __restrict__ Qp2, float* __restrict__ Qpc) {
  const int lg = (blockIdx.x & 7) * 32 + (blockIdx.x >> 3);  // logical 0..255
  const int by = lg >> 3;                       // 0..31  (m-tiles of 128)
  const int bx = lg & 7;                        // 0..7   (n-tiles of 128)
  const int lane = threadIdx.x & 63, wave = threadIdx.x >> 6;  // wave 0..7
  const int wm = wave >> 2, wn = wave & 3;
  const int lr = lane & 31, kh = lane >> 5;

  __shared__ __align__(16) short As[2][2][4][2][512];  // 32 KiB
  __shared__ __align__(16) short Bs[2][2][4][2][512];  // 32 KiB

  floatx16 acc[2];
  #pragma unroll
  for (int i = 0; i < 2; ++i)
    #pragma unroll
    for (int t = 0; t < 16; ++t) acc[i][t] = 0.f;

#define STAGE(SI) do { int buf_ = (SI) & 1, kt0_ = (SI) * 2; \
    _Pragma("unroll") for (int q_ = 0; q_ < 4; ++q_) { \
      int f_ = wave * 4 + q_; \
      if (f_ < 16) { \
        int hl_ = f_ & 1, mt_ = (f_ >> 1) & 3, ktl_ = f_ >> 3; \
        const unsigned short* gb_ = (hl_ ? Al : Ah) + \
            (((size_t)(by * 4 + mt_) * 64 + kt0_ + ktl_) * 64 + lane) * 8; \
        gl2lds16(gb_, &As[buf_][ktl_][mt_][hl_][0]); \
      } else { \
        int r_ = f_ - 16, hl_ = r_ & 1, nt_ = (r_ >> 1) & 3, ktl_ = r_ >> 3; \
        const unsigned short* gb_ = (hl_ ? Bl : Bh) + \
            (((size_t)(bx * 4 + nt_) * 64 + kt0_ + ktl_) * 64 + lane) * 8; \
        gl2lds16(gb_, &Bs[buf_][ktl_][nt_][hl_][0]); \
      } } } while (0)

  STAGE(0);
  for (int s = 0; s < 32; ++s) {
    __syncthreads();
    if (s + 1 < 32) STAGE(s + 1);
    const int buf = s & 1;
    #pragma unroll
    for (int ktl = 0; ktl < 2; ++ktl) {
      short8 a[2][2], b[2];
      #pragma unroll
      for (int i = 0; i < 2; ++i) {
        a[i][0] = *(const short8*)&As[buf][ktl][wm * 2 + i][0][lane * 8];
        a[i][1] = *(const short8*)&As[buf][ktl][wm * 2 + i][1][lane * 8];
      }
      b[0] = *(const short8*)&Bs[buf][ktl][wn][0][lane * 8];
      b[1] = *(const short8*)&Bs[buf][ktl][wn][1][lane * 8];
      #pragma unroll
      for (int i = 0; i < 2; ++i) {
        acc[i] = __builtin_amdgcn_mfma_f32_32x32x16_bf16(a[i][0], b[0], acc[i], 0, 0, 0);
        acc[i] = __builtin_amdgcn_mfma_f32_32x32x16_bf16(a[i][0], b[1], acc[i], 0, 0, 0);
        acc[i] = __builtin_amdgcn_mfma_f32_32x32x16_bf16(a[i][1], b[0], acc[i], 0, 0, 0);
      }
    }
  }
#undef STAGE

  // Epilogue: Yt[n*4096+m] float4 stores + per-column stats.
  float st1 = 0.f, st2 = 0.f, stc = 0.f;
  int n = bx * 128 + wn * 32 + lr;
  #pragma unroll
  for (int i = 0; i < 2; ++i) {
    int mbase = by * 128 + (wm * 2 + i) * 32 + 4 * kh;
    #pragma unroll
    for (int rq = 0; rq < 4; ++rq) {
      float4 v4;
      v4.x = acc[i][rq * 4 + 0];
      v4.y = acc[i][rq * 4 + 1];
      v4.z = acc[i][rq * 4 + 2];
      v4.w = acc[i][rq * 4 + 3];
      *(float4*)&Yt[(size_t)n * 4096 + mbase + rq * 8] = v4;
      #pragma unroll
      for (int e = 0; e < 4; ++e) {
        float v = (&v4.x)[e];
        st1 += v;
        st2 = fmaf(v, v, st2);
        stc += (fabsf(v) < 0.1f) ? 1.f : 0.f;
      }
    }
  }
  __syncthreads();                              // all As/Bs reads done
  // Stats arrays alias the (now dead) As buffer -> LDS stays at 64 KiB.
  float* sS1 = (float*)&As[0][0][0][0][0];
  float* sS2 = sS1 + 128;
  float* sC  = sS1 + 256;
  if (threadIdx.x < 128) { sS1[threadIdx.x] = 0.f; sS2[threadIdx.x] = 0.f; sC[threadIdx.x] = 0.f; }
  __syncthreads();
  {
    int cl = wn * 32 + lr;
    atomicAdd(&sS1[cl], st1);
    atomicAdd(&sS2[cl], st2);
    atomicAdd(&sC[cl], stc);
  }
  __syncthreads();
  if (threadIdx.x < 128) {
    int part = by & 3, k3 = by >> 2;
    size_t qo = ((size_t)part * 8 + k3) * 1024 + bx * 128 + threadIdx.x;
    Qp1[qo] = sS1[threadIdx.x];
    Qp2[qo] = sS2[threadIdx.x];
    Qpc[qo] = sC[threadIdx.x];
  }
}

// ---------------------------------------------------------------------------
// Fused selection + collapse. Each of the 8 chunk-blocks per batch redundantly
// computes the same top-64 selection (set is order-independent), then collapses.
__global__ __launch_bounds__(256) void collapse2(
    const float* __restrict__ Yt,
    const float* __restrict__ Qp1, const float* __restrict__ Qp2,
    const float* __restrict__ Qpc, const float* __restrict__ coeff,
    float* __restrict__ out) {
  int b = blockIdx.x >> 3, chunk = blockIdx.x & 7;
  int lane = threadIdx.x & 63, wv = threadIdx.x >> 6;
  int tid = threadIdx.x;
  __shared__ float q[NPATH];
  __shared__ int ls[MAXP];
  __shared__ int cnt;
  __shared__ float s_sum[4][64], s_best[4][64], s_ba[4][64];
  if (tid == 0) cnt = 0;
  float c0 = coeff[b * 4 + 0], c1 = coeff[b * 4 + 1], c2w = coeff[b * 4 + 2];
  for (int p = tid; p < NPATH; p += 256) {
    int k3 = p >> 6, k2 = (p >> 3) & 7, k1 = p & 7;
    int c2 = k2 * 128 + k1 * 16 + b;
    float S1 = 0.f, S2 = 0.f, C = 0.f;
    #pragma unroll
    for (int part = 0; part < 4; ++part) {
      size_t qo = ((size_t)part * 8 + k3) * 1024 + c2;
      S1 += Qp1[qo]; S2 += Qp2[qo]; C += Qpc[qo];
    }
    float strength = sqrtf(S2);
    float sparsity = C * (1.f / 512.f);
    float diversity = (S2 - S1 * S1 * (1.f / 512.f)) * (1.f / 511.f);
    q[p] = c0 * strength + c1 * sparsity + c2w * diversity;
  }
  __syncthreads();
  for (int p = tid; p < NPATH; p += 256) {
    float qp = q[p];
    int rank = 0;
    #pragma unroll 8
    for (int j = 0; j < NPATH; ++j) {
      float qj = q[j];
      rank += (qj > qp) || (qj == qp && j < p);
    }
    if (rank < MAXP) {
      int sl = atomicAdd(&cnt, 1);
      ls[sl] = p;
    }
  }
  __syncthreads();
  int o3 = chunk * 64 + lane;
  float sum = 0.f, best = 0.f, besta = -1.f;
  #pragma unroll 4
  for (int j = wv * 16; j < wv * 16 + 16; ++j) {
    int p = ls[j];
    int k3 = p >> 6, k2 = (p >> 3) & 7, k1 = p & 7;
    int col = k2 * 128 + k1 * 16 + b;
    float v = Yt[(size_t)col * 4096 + k3 * 512 + o3];
    sum += v;
    float a = fabsf(v);
    if (a > besta) { besta = a; best = v; }
  }
  s_sum[wv][lane] = sum; s_best[wv][lane] = best; s_ba[wv][lane] = besta;
  __syncthreads();
  if (tid < 64) {
    float S = 0.f, BV = 0.f, BA = -1.f;
    #pragma unroll
    for (int w2 = 0; w2 < 4; ++w2) {
      S += s_sum[w2][tid];
      if (s_ba[w2][tid] > BA) { BA = s_ba[w2][tid]; BV = s_best[w2][tid]; }
    }
    float alpha = coeff[b * 4 + 3];
    out[b * 512 + chunk * 64 + tid] = (1.f - alpha) * (S * (1.f / 64.f)) + alpha * BV;
  }
}

// ---------------------------------------------------------------------------
extern "C" void kernel_launch(void* const* d_in, const int* in_sizes, int n_in,
                              void* d_out, int out_size, void* d_ws, size_t ws_size,
                              hipStream_t stream) {
  const float* x   = (const float*)d_in[0];
  const float* W1  = (const float*)d_in[1];
  const float* W2  = (const float*)d_in[2];
  const float* W3  = (const float*)d_in[3];
  const float* sW1 = (const float*)d_in[4];
  const float* sb1 = (const float*)d_in[5];
  const float* sW2 = (const float*)d_in[6];
  const float* sb2 = (const float*)d_in[7];
  const float* sW3 = (const float*)d_in[8];
  const float* sb3 = (const float*)d_in[9];
  float* out = (float*)d_out;                   // 16*512 outputs + 16*16 sigma

  char* w = (char*)d_ws;
  float* XT = (float*)w;                       w += 65536;     // 1024x16 f32
  unsigned short* W3h = (unsigned short*)w;    w += 8388608;   // 4096x1024 bf16 swz
  unsigned short* W3l = (unsigned short*)w;    w += 8388608;
  unsigned short* X2th = (unsigned short*)w;   w += 262144;    // 128x1024 bf16 swz
  unsigned short* X2tl = (unsigned short*)w;   w += 262144;
  unsigned short* X3th = (unsigned short*)w;   w += 2097152;   // 1024x1024 bf16 swz
  unsigned short* X3tl = (unsigned short*)w;   w += 2097152;
  float* Yt    = (float*)w;                    w += 16777216;  // 1024x4096 f32 (transposed)
  float* Pp    = (float*)w;                    w += 16777216;  // 4x128x8192 f32 (L2 partials)
  float* Xp    = (float*)w;                    w += 2097152;   // 4x16x8192 f32 (L1 partials)
  float* coeff = (float*)w;                    w += 256;
  float* Qp1   = (float*)w;                    w += 131072;    // 4x8x1024 f32
  float* Qp2   = (float*)w;                    w += 131072;
  float* Qpc   = (float*)w;                    w += 131072;
  float* h1    = (float*)w;                    w += 4096;

  sigma_stage1<<<256, 256, 0, stream>>>(x, sW1, sb1, h1, XT);

  // L1a GEMM + sigma stage 2 (one launch; block 256 = sigma2, runs concurrently)
  gemm_l1a_sigma2<<<257, 256, 0, stream>>>(
      W1, XT, Xp, h1, sW2, sb2, sW3, sb3, out + 8192, coeff);

  // L1 reduce + W3 split
  gemm_l1red_w3split<<<2176, 256, 0, stream>>>(Xp, X2th, X2tl, W3, W3h, W3l);

  // L2: MFMA 64x128, full-N, split-K 4 (512 blocks, 2/CU), in-kernel W2 split
  mfma_l2<<<512, 256, 0, stream>>>(W2, X2th, X2tl, Pp);
  gemm_l2red<<<1024, 256, 0, stream>>>(Pp, X3th, X3tl);

  // L3: MFMA 128x128, full K (256 blocks x 512 thr, XCD-swizzled),
  // pre-split A via global_load_lds, writes Yt + stats
  mfma_l3<<<256, 512, 0, stream>>>(W3h, W3l, X3th, X3tl, Yt, Qp1, Qp2, Qpc);

  // Fused selection + collapse
  collapse2<<<128, 256, 0, stream>>>(Yt, Qp1, Qp2, Qpc, coeff, out);
}